// Round 1
// baseline (30.547 us; speedup 1.0000x reference)
//
#include <hip/hip_runtime.h>
#include <hip/hip_bf16.h>
#include <math.h>

#define NUM_WIRES 512
#define BATCH 65536

// Prep: coeff[j] = head_w[j] * 2*exp(-squeeze2[j])*exp(-squeeze[j])*cos(phase[j])
//       bias    = head_b[0] + sum_j head_w[j] * 2*exp(-squeeze2[j])*disp[j]
// coeff_bias layout in d_ws: [0..511] coeff, [512] bias
__global__ void prep_kernel(const float* __restrict__ squeeze,
                            const float* __restrict__ phase,
                            const float* __restrict__ disp,
                            const float* __restrict__ squeeze2,
                            const float* __restrict__ head_w,
                            const float* __restrict__ head_b,
                            float* __restrict__ coeff_bias) {
    const int j = threadIdx.x;          // 512 threads, 1 block
    const float root2h = 2.0f;          // sqrt(2*HBAR), HBAR=2
    float e2 = __expf(-squeeze2[j]);
    // use expf/cosf full-precision versions to stay close to numpy f32
    e2 = expf(-squeeze2[j]);
    const float a = root2h * e2 * expf(-squeeze[j]) * cosf(phase[j]);
    const float w = head_w[j];
    coeff_bias[j] = w * a;

    // block-reduce the constant part
    __shared__ float red[NUM_WIRES];
    red[j] = w * root2h * e2 * disp[j];
    __syncthreads();
    for (int s = NUM_WIRES / 2; s > 0; s >>= 1) {
        if (j < s) red[j] += red[j + s];
        __syncthreads();
    }
    if (j == 0) coeff_bias[NUM_WIRES] = red[0] + head_b[0];
}

// One row per wave: 64 lanes x 2 float4 = 512 floats, coalesced.
__global__ __launch_bounds__(256) void dot_kernel(const float* __restrict__ x,
                                                  const float* __restrict__ coeff_bias,
                                                  float* __restrict__ out,
                                                  int rows) {
    const int lane = threadIdx.x & 63;
    const int waveInBlock = threadIdx.x >> 6;
    const int wavesPerBlock = blockDim.x >> 6;   // 4
    const int waveStride = gridDim.x * wavesPerBlock;

    // Per-lane coeff fragment is invariant across rows — hoist to registers.
    const float4 c0 = *reinterpret_cast<const float4*>(coeff_bias + lane * 4);
    const float4 c1 = *reinterpret_cast<const float4*>(coeff_bias + 256 + lane * 4);
    const float bias = coeff_bias[NUM_WIRES];

    for (int row = blockIdx.x * wavesPerBlock + waveInBlock; row < rows; row += waveStride) {
        const float4* p = reinterpret_cast<const float4*>(x + (size_t)row * NUM_WIRES);
        const float4 a = p[lane];
        const float4 b = p[64 + lane];
        float s = a.x * c0.x + a.y * c0.y + a.z * c0.z + a.w * c0.w
                + b.x * c1.x + b.y * c1.y + b.z * c1.z + b.w * c1.w;
        // 64-lane butterfly reduce
        #pragma unroll
        for (int off = 32; off >= 1; off >>= 1)
            s += __shfl_xor(s, off, 64);
        if (lane == 0) out[row] = s + bias;
    }
}

extern "C" void kernel_launch(void* const* d_in, const int* in_sizes, int n_in,
                              void* d_out, int out_size, void* d_ws, size_t ws_size,
                              hipStream_t stream) {
    const float* state_batch = (const float*)d_in[0];  // (65536, 512)
    const float* squeeze     = (const float*)d_in[1];  // (512,)
    const float* phase       = (const float*)d_in[2];  // (512,)
    const float* disp        = (const float*)d_in[3];  // (512,)
    const float* squeeze2    = (const float*)d_in[4];  // (512,)
    // d_in[5] = kerr — unused by the reference output
    const float* head_w      = (const float*)d_in[6];  // (1, 512)
    const float* head_b      = (const float*)d_in[7];  // (1,)
    float* out = (float*)d_out;
    float* coeff_bias = (float*)d_ws;                  // 513 floats

    prep_kernel<<<1, NUM_WIRES, 0, stream>>>(squeeze, phase, disp, squeeze2,
                                             head_w, head_b, coeff_bias);
    dot_kernel<<<2048, 256, 0, stream>>>(state_batch, coeff_bias, out, out_size);
}

// Round 2
// 26.764 us; speedup vs baseline: 1.1414x; 1.1414x over previous
//
#include <hip/hip_runtime.h>
#include <hip/hip_bf16.h>
#include <math.h>

#define NUM_WIRES 512

// Fully fused: out[b] = sum_j coeff[j]*x[b,j] + bias
//   coeff[j] = head_w[j] * 2*exp(-squeeze2[j])*exp(-squeeze[j])*cos(phase[j])
//   bias     = head_b[0] + sum_j head_w[j] * 2*exp(-squeeze2[j])*disp[j]
// (sqrt(2*HBAR) = 2 exactly since HBAR = 2; kerr is dead in the reference.)
// Each block recomputes coeff+bias in LDS (cheap VALU, hides under streaming).
__global__ __launch_bounds__(256, 8) void fused_dot_kernel(
        const float* __restrict__ x,
        const float* __restrict__ squeeze,
        const float* __restrict__ phase,
        const float* __restrict__ disp,
        const float* __restrict__ squeeze2,
        const float* __restrict__ head_w,
        const float* __restrict__ head_b,
        float* __restrict__ out, int rows) {
    __shared__ float s_coeff[NUM_WIRES];
    __shared__ float s_red[256];

    const int t = threadIdx.x;
    float partial = 0.0f;
    #pragma unroll
    for (int k = 0; k < 2; ++k) {
        const int j = t + k * 256;
        const float e2 = expf(-squeeze2[j]);
        const float w  = head_w[j];
        s_coeff[j] = w * 2.0f * e2 * expf(-squeeze[j]) * cosf(phase[j]);
        partial += w * 2.0f * e2 * disp[j];
    }
    s_red[t] = partial;
    __syncthreads();
    #pragma unroll
    for (int s = 128; s > 0; s >>= 1) {
        if (t < s) s_red[t] += s_red[t + s];
        __syncthreads();
    }
    const float bias = s_red[0] + head_b[0];

    const int lane = t & 63;
    const int wave = t >> 6;
    // Per-lane coeff fragment, invariant across rows.
    const float4 c0 = *reinterpret_cast<const float4*>(&s_coeff[lane * 4]);
    const float4 c1 = *reinterpret_cast<const float4*>(&s_coeff[256 + lane * 4]);

    // 2048 blocks x 4 waves = 8192 waves; each wave owns 8 consecutive rows,
    // processed 2 at a time (4 float4 loads in flight).
    const int waveId = blockIdx.x * 4 + wave;
    const int base = waveId * 8;
    #pragma unroll
    for (int i = 0; i < 4; ++i) {
        const int r0 = base + 2 * i;
        if (r0 + 1 >= rows + 1) break;  // rows==65536 always; keep guard cheap
        const float4* p0 = reinterpret_cast<const float4*>(x + (size_t)r0 * NUM_WIRES);
        const float4* p1 = reinterpret_cast<const float4*>(x + (size_t)(r0 + 1) * NUM_WIRES);
        const float4 a0 = p0[lane];
        const float4 b0 = p0[64 + lane];
        const float4 a1 = p1[lane];
        const float4 b1 = p1[64 + lane];
        float s0 = a0.x * c0.x + a0.y * c0.y + a0.z * c0.z + a0.w * c0.w
                 + b0.x * c1.x + b0.y * c1.y + b0.z * c1.z + b0.w * c1.w;
        float s1 = a1.x * c0.x + a1.y * c0.y + a1.z * c0.z + a1.w * c0.w
                 + b1.x * c1.x + b1.y * c1.y + b1.z * c1.z + b1.w * c1.w;
        // two independent 64-lane butterflies (interleaved for ILP)
        #pragma unroll
        for (int off = 32; off >= 1; off >>= 1) {
            s0 += __shfl_xor(s0, off, 64);
            s1 += __shfl_xor(s1, off, 64);
        }
        if (lane == 0) out[r0] = s0 + bias;
        if (lane == 1 && r0 + 1 < rows) out[r0 + 1] = s1 + bias;
    }
}

extern "C" void kernel_launch(void* const* d_in, const int* in_sizes, int n_in,
                              void* d_out, int out_size, void* d_ws, size_t ws_size,
                              hipStream_t stream) {
    const float* state_batch = (const float*)d_in[0];  // (65536, 512)
    const float* squeeze     = (const float*)d_in[1];
    const float* phase       = (const float*)d_in[2];
    const float* disp        = (const float*)d_in[3];
    const float* squeeze2    = (const float*)d_in[4];
    // d_in[5] = kerr — unused by the reference output
    const float* head_w      = (const float*)d_in[6];
    const float* head_b      = (const float*)d_in[7];
    float* out = (float*)d_out;

    fused_dot_kernel<<<2048, 256, 0, stream>>>(state_batch, squeeze, phase, disp,
                                               squeeze2, head_w, head_b, out, out_size);
}

// Round 3
// 26.271 us; speedup vs baseline: 1.1628x; 1.0187x over previous
//
#include <hip/hip_runtime.h>
#include <hip/hip_bf16.h>
#include <math.h>

#define NUM_WIRES 512

typedef float f4 __attribute__((ext_vector_type(4)));

__device__ __forceinline__ f4 ntload(const f4* p) {
    return __builtin_nontemporal_load(p);
}

__device__ __forceinline__ float dot8(f4 a, f4 b, f4 ca, f4 cb) {
    return a[0]*ca[0] + a[1]*ca[1] + a[2]*ca[2] + a[3]*ca[3]
         + b[0]*cb[0] + b[1]*cb[1] + b[2]*cb[2] + b[3]*cb[3];
}

// out[b] = sum_j coeff[j]*x[b,j] + bias
//   coeff[j] = head_w[j] * 2*exp(-squeeze2[j])*exp(-squeeze[j])*cos(phase[j])
//   bias     = head_b[0] + sum_j head_w[j] * 2*exp(-squeeze2[j])*disp[j]
// (sqrt(2*HBAR)=2 exactly; kerr is dead.)
// Barrier-free: each lane computes only its own 8 coeffs; bias via one butterfly.
__global__ __launch_bounds__(256, 4) void fused_dot_kernel(
        const float* __restrict__ x,
        const float* __restrict__ squeeze,
        const float* __restrict__ phase,
        const float* __restrict__ disp,
        const float* __restrict__ squeeze2,
        const float* __restrict__ head_w,
        const float* __restrict__ head_b,
        float* __restrict__ out, int rows) {
    const int t = threadIdx.x;
    const int lane = t & 63;
    const int wave = t >> 6;
    const int waveId = blockIdx.x * 4 + wave;
    const int base = waveId * 8;               // 8 rows per wave
    if (base >= rows) return;

    // ---- per-lane coeff fragment (columns lane*4..+3 and 256+lane*4..+3) ----
    const f4 sqa = ((const f4*)squeeze )[lane], sqb = ((const f4*)squeeze )[64 + lane];
    const f4 pha = ((const f4*)phase   )[lane], phb = ((const f4*)phase   )[64 + lane];
    const f4 dia = ((const f4*)disp    )[lane], dib = ((const f4*)disp    )[64 + lane];
    const f4 s2a = ((const f4*)squeeze2)[lane], s2b = ((const f4*)squeeze2)[64 + lane];
    const f4 wa  = ((const f4*)head_w  )[lane], wb  = ((const f4*)head_w  )[64 + lane];

    f4 c0, c1;
    float part = 0.0f;
    #pragma unroll
    for (int k = 0; k < 4; ++k) {
        const float e2a = expf(-s2a[k]);
        const float e2b = expf(-s2b[k]);
        c0[k] = wa[k] * 2.0f * e2a * expf(-sqa[k]) * cosf(pha[k]);
        c1[k] = wb[k] * 2.0f * e2b * expf(-sqb[k]) * cosf(phb[k]);
        part += wa[k] * 2.0f * e2a * dia[k] + wb[k] * 2.0f * e2b * dib[k];
    }
    #pragma unroll
    for (int off = 32; off >= 1; off >>= 1)
        part += __shfl_xor(part, off, 64);
    const float bias = part + head_b[0];

    // ---- stream 8 rows, 4 per iteration (8 float4 loads in flight) ----
    const f4* xb = (const f4*)(x + (size_t)base * NUM_WIRES);   // 128 f4 per row
    #pragma unroll
    for (int i = 0; i < 2; ++i) {
        const int r0 = base + i * 4;
        const f4* p = xb + (size_t)i * 4 * 128;
        const f4 a0 = ntload(p +        lane), b0 = ntload(p +  64 + lane);
        const f4 a1 = ntload(p + 128 +  lane), b1 = ntload(p + 192 + lane);
        const f4 a2 = ntload(p + 256 +  lane), b2 = ntload(p + 320 + lane);
        const f4 a3 = ntload(p + 384 +  lane), b3 = ntload(p + 448 + lane);

        float s0 = dot8(a0, b0, c0, c1);
        float s1 = dot8(a1, b1, c0, c1);
        float s2 = dot8(a2, b2, c0, c1);
        float s3 = dot8(a3, b3, c0, c1);

        // paired butterfly: 4 rows in 10 shfls
        s0 += __shfl_xor(s0, 32, 64);
        s1 += __shfl_xor(s1, 32, 64);
        s2 += __shfl_xor(s2, 32, 64);
        s3 += __shfl_xor(s3, 32, 64);
        float u0 = (lane & 32) ? s1 : s0;   // halves: row0 | row1
        float u1 = (lane & 32) ? s3 : s2;   // halves: row2 | row3
        u0 += __shfl_xor(u0, 16, 64);
        u1 += __shfl_xor(u1, 16, 64);
        float v = (lane & 16) ? u1 : u0;    // 16-groups: row0|row2|row1|row3
        v += __shfl_xor(v, 8, 64);
        v += __shfl_xor(v, 4, 64);
        v += __shfl_xor(v, 2, 64);
        v += __shfl_xor(v, 1, 64);

        if ((lane & 15) == 0) {
            const int roff = ((lane >> 4) & 1) * 2 + (lane >> 5);  // 0,2,1,3
            const int r = r0 + roff;
            if (r < rows) out[r] = v + bias;
        }
    }
}

extern "C" void kernel_launch(void* const* d_in, const int* in_sizes, int n_in,
                              void* d_out, int out_size, void* d_ws, size_t ws_size,
                              hipStream_t stream) {
    const float* state_batch = (const float*)d_in[0];  // (65536, 512)
    const float* squeeze     = (const float*)d_in[1];
    const float* phase       = (const float*)d_in[2];
    const float* disp        = (const float*)d_in[3];
    const float* squeeze2    = (const float*)d_in[4];
    // d_in[5] = kerr — unused by the reference output
    const float* head_w      = (const float*)d_in[6];
    const float* head_b      = (const float*)d_in[7];
    float* out = (float*)d_out;

    fused_dot_kernel<<<2048, 256, 0, stream>>>(state_batch, squeeze, phase, disp,
                                               squeeze2, head_w, head_b, out, out_size);
}